// Round 5
// baseline (144.660 us; speedup 1.0000x reference)
//
#include <hip/hip_runtime.h>
#include <hip/hip_bf16.h>

// HyperPatchConv2d: B=2, CIN=COUT=64, H=W=256, FH=FW=16 (16x16 patches), SC=128, K=3, reflect pad.
// Pipeline (3 kernels):
//   prep_xs: x fp32 -> xT bf16 channel-last [b][h][w][64ci]; blocks 0-1 also build
//            sT bf16 [512 patch][128 k] from s.
//   wgen:    MFMA GEMM, grid 288 m-tiles, n-loop over 4 chunks of 128 patches inside the
//            block (s2w fetched ONCE). M-index == conv-fragment linear offset o:
//              o = fragidx*512 + lane*8 + j, fragidx=(tap*2+ks)*4+mt, lane=(co&15)+16*quad,
//              ci = ks*32+quad*8+j, co = mt*16+(lane&15), p(s2w row) = co*576+ci*9+tap.
//            Epilogue transposes C through LDS (reusing Bs, two 64-patch halves) so each
//            patch gets contiguous 256B stores.
//   conv:    per-patch 9-tap MFMA GEMM; 8 waves, wave owns mt-pair (w&1) x row-quarter (w>>1).

#define C_OUT 64
#define C_IN  64
#define P_TOTAL 36864
#define N_PATCH 512
#define WSTR 72          // shorts per (r,c) cell in conv window LDS (144B)
#define GPLANE 1032      // shorts per k8-plane in wgen LDS (516 dwords = 4 mod 32)
#define CSTR 136         // shorts per patch-row in wgen epilogue LDS (272B, 16B-aligned)

typedef __bf16 bf16x8 __attribute__((ext_vector_type(8)));
typedef float  f32x4  __attribute__((ext_vector_type(4)));

__device__ __forceinline__ unsigned short f2bf(float f) {
  unsigned int u = __float_as_uint(f);
  u += 0x7fffu + ((u >> 16) & 1u);   // RTNE on bf16 boundary
  return (unsigned short)(u >> 16);
}

// ---------- prep: x -> xT (all blocks); s -> sT (blocks 0-1) ----------
__global__ __launch_bounds__(256) void prep_xs(
    const float* __restrict__ x, const float* __restrict__ s,
    unsigned short* __restrict__ xT, unsigned short* __restrict__ sT) {
  __shared__ unsigned short lds[256 * 68];
  const int bb = blockIdx.x >> 8;
  const int row = blockIdx.x & 255;
  const int t = threadIdx.x;
  const float* src = x + ((size_t)bb * 64) * 65536 + row * 256 + t;
  #pragma unroll 8
  for (int ci = 0; ci < 64; ++ci)
    lds[t * 68 + ci] = f2bf(src[(size_t)ci * 65536]);
  __syncthreads();
  unsigned short* dst = xT + ((size_t)(bb * 65536 + row * 256 + t)) * 64;
  #pragma unroll
  for (int k8 = 0; k8 < 8; ++k8) {
    const uint2 u0 = *(const uint2*)&lds[t * 68 + k8 * 8];
    const uint2 u1 = *(const uint2*)&lds[t * 68 + k8 * 8 + 4];
    *(uint4*)(dst + k8 * 8) = make_uint4(u0.x, u0.y, u1.x, u1.y);
  }
  if (blockIdx.x < 2) {   // fold in prep_s: one block per batch
    const int sb = blockIdx.x;
    unsigned short* sd = sT + ((size_t)sb * 256 + t) * 128;
    for (int k = 0; k < 128; k += 2) {
      const float a = s[(size_t)(sb * 128 + k) * 256 + t];
      const float b = s[(size_t)(sb * 128 + k + 1) * 256 + t];
      *(unsigned int*)(sd + k) = (unsigned int)f2bf(a) | ((unsigned int)f2bf(b) << 16);
    }
  }
}

// ---------- wgen: MFMA GEMM, 128-m tile, internal loop over 4 x 128-patch chunks ----------
__global__ __launch_bounds__(256) void wgen_kernel(
    const float* __restrict__ s2w,          // fp32 [36864][128]
    const unsigned short* __restrict__ sT,  // bf16 [512][128]
    unsigned short* __restrict__ wout)      // bf16 frags [512][36864], offset o == m
{
  __shared__ unsigned short As[16 * GPLANE];   // 33 KB, written once
  __shared__ unsigned short Bs[16 * GPLANE];   // 33 KB, reused as Ct (64 x CSTR) in epilogue
  const int tid = threadIdx.x;
  const int m0 = blockIdx.x * 128;   // 288 blocks

  const int fragidx = m0 >> 9;
  const int tap = fragidx >> 3;
  const int ksH = (fragidx >> 2) & 1;
  const int mtH = fragidx & 3;

  // A staging: permute + f2bf from fp32 s2w (once per block)
  #pragma unroll
  for (int i = 0; i < 8; ++i) {
    const int chunk = i * 256 + tid;        // 2048 chunks: 128 rows x 16 planes
    const int row = chunk >> 4;
    const int g = chunk & 15;
    const int m = m0 + row;
    const int j = m & 7;
    const int lane6 = (m >> 3) & 63;
    const int co = mtH * 16 + (lane6 & 15);
    const int ci = ksH * 32 + (lane6 >> 4) * 8 + j;
    const int p = co * 576 + ci * 9 + tap;
    const float* srcp = s2w + (size_t)p * 128 + g * 8;
    const float4 v0 = *(const float4*)srcp;
    const float4 v1 = *(const float4*)(srcp + 4);
    uint4 o;
    o.x = (unsigned int)f2bf(v0.x) | ((unsigned int)f2bf(v0.y) << 16);
    o.y = (unsigned int)f2bf(v0.z) | ((unsigned int)f2bf(v0.w) << 16);
    o.z = (unsigned int)f2bf(v1.x) | ((unsigned int)f2bf(v1.y) << 16);
    o.w = (unsigned int)f2bf(v1.z) | ((unsigned int)f2bf(v1.w) << 16);
    *(uint4*)&As[g * GPLANE + row * 8] = o;
  }

  const int wave = tid >> 6;
  const int lane = tid & 63;
  const int col = lane & 15;
  const int quad = lane >> 4;

  for (int n0 = 0; n0 < 512; n0 += 128) {
    // B staging: bf16 sT chunk (L2-resident after first block touches it)
    #pragma unroll
    for (int i = 0; i < 8; ++i) {
      const int chunk = i * 256 + tid;
      const int row = chunk >> 4;
      const int g = chunk & 15;
      *(uint4*)&Bs[g * GPLANE + row * 8] = *(const uint4*)(sT + ((size_t)(n0 + row)) * 128 + g * 8);
    }
    __syncthreads();   // covers A (first iter) + B

    f32x4 acc[2][8] = {};
    #pragma unroll
    for (int ks = 0; ks < 4; ++ks) {
      const int g = ks * 4 + quad;
      bf16x8 afr[2], bfr[8];
      #pragma unroll
      for (int mti = 0; mti < 2; ++mti)
        afr[mti] = *(const bf16x8*)&As[g * GPLANE + ((wave * 2 + mti) * 16 + col) * 8];
      #pragma unroll
      for (int nt = 0; nt < 8; ++nt)
        bfr[nt] = *(const bf16x8*)&Bs[g * GPLANE + (nt * 16 + col) * 8];
      #pragma unroll
      for (int mti = 0; mti < 2; ++mti)
        #pragma unroll
        for (int nt = 0; nt < 8; ++nt)
          acc[mti][nt] = __builtin_amdgcn_mfma_f32_16x16x32_bf16(afr[mti], bfr[nt], acc[mti][nt], 0, 0, 0);
    }
    __syncthreads();   // B reads done; Bs region becomes Ct

    // Epilogue: two 64-patch halves through LDS -> contiguous 256B/patch stores
    unsigned short* Ct = Bs;
    #pragma unroll
    for (int half = 0; half < 2; ++half) {
      #pragma unroll
      for (int mti = 0; mti < 2; ++mti) {
        const int mloc = (wave * 2 + mti) * 16 + quad * 4;
        #pragma unroll
        for (int nt2 = 0; nt2 < 4; ++nt2) {
          const int nt = half * 4 + nt2;
          const int pl = nt2 * 16 + col;     // 0..63
          ushort4 o;
          o.x = f2bf(acc[mti][nt][0]); o.y = f2bf(acc[mti][nt][1]);
          o.z = f2bf(acc[mti][nt][2]); o.w = f2bf(acc[mti][nt][3]);
          *(ushort4*)&Ct[pl * CSTR + mloc] = o;
        }
      }
      __syncthreads();
      #pragma unroll
      for (int i = 0; i < 4; ++i) {
        const int chunk = i * 256 + tid;     // 1024: 64 patches x 16 chunks of 16B
        const int pl = chunk >> 4;
        const int ii = chunk & 15;
        const uint4 v = *(const uint4*)&Ct[pl * CSTR + ii * 8];
        *(uint4*)(wout + (size_t)(n0 + half * 64 + pl) * P_TOTAL + m0 + ii * 8) = v;
      }
      __syncthreads();   // drain done before Ct rewrite / next B staging
    }
  }
}

// ---------- conv: per-patch MFMA; wave = (mt-pair, row-quarter) ----------
__global__ __launch_bounds__(512) void conv_kernel(
    const unsigned short* __restrict__ xT,     // bf16 [2][256][256][64]
    const unsigned short* __restrict__ wfrag,  // bf16 frags [512][36864]
    float* __restrict__ out)                   // [2][64][256][256]
{
  __shared__ unsigned short win[324 * WSTR];   // 46656 B
  const int tid = threadIdx.x;
  const int patch = blockIdx.x;
  const int bb = patch >> 8;
  const int fg = patch & 255;
  const int f = fg >> 4, g = fg & 15;
  const int row0 = f * 16, col0 = g * 16;

  for (int chunk = tid; chunk < 2592; chunk += 512) {
    const int cell = chunk >> 3;
    const int j = chunk & 7;
    const int r = cell / 18;
    const int c = cell - r * 18;
    int rr = row0 + r - 1; rr = rr < 0 ? -rr : (rr > 255 ? 510 - rr : rr);
    int cc = col0 + c - 1; cc = cc < 0 ? -cc : (cc > 255 ? 510 - cc : cc);
    *(uint4*)&win[cell * WSTR + j * 8] =
        *(const uint4*)(xT + ((size_t)((bb << 16) + (rr << 8) + cc)) * 64 + j * 8);
  }
  __syncthreads();

  const int wave = tid >> 6;
  const int lane = tid & 63;
  const int t = lane & 15;
  const int quad = lane >> 4;
  const int mh = wave & 1;        // mt pair: mh*2 + {0,1}
  const int rq = wave >> 1;       // rows rq*4 + {0..3}

  f32x4 acc[2][4] = {};           // [ml][nt]
  const bf16x8* wb = (const bf16x8*)(wfrag + (size_t)patch * P_TOTAL);

  #pragma unroll
  for (int tap = 0; tap < 9; ++tap) {
    const int ti = tap / 3;
    const int tj = tap - ti * 3;
    bf16x8 afr[2][2];
    #pragma unroll
    for (int ks = 0; ks < 2; ++ks)
      #pragma unroll
      for (int ml = 0; ml < 2; ++ml)
        afr[ks][ml] = wb[((tap * 2 + ks) * 4 + mh * 2 + ml) * 64 + lane];

    #pragma unroll
    for (int nt = 0; nt < 4; ++nt) {
      const int r = rq * 4 + nt + ti;
      const int c = t + tj;
      const int base = (r * 18 + c) * WSTR + quad * 8;
      #pragma unroll
      for (int ks = 0; ks < 2; ++ks) {
        const bf16x8 bfr = *(const bf16x8*)&win[base + ks * 32];
        acc[0][nt] = __builtin_amdgcn_mfma_f32_16x16x32_bf16(afr[ks][0], bfr, acc[0][nt], 0, 0, 0);
        acc[1][nt] = __builtin_amdgcn_mfma_f32_16x16x32_bf16(afr[ks][1], bfr, acc[1][nt], 0, 0, 0);
      }
    }
  }

  #pragma unroll
  for (int ml = 0; ml < 2; ++ml) {
    #pragma unroll
    for (int nt = 0; nt < 4; ++nt) {
      const int p = row0 + rq * 4 + nt;
      #pragma unroll
      for (int reg = 0; reg < 4; ++reg) {
        const int co = (mh * 2 + ml) * 16 + quad * 4 + reg;
        out[(((size_t)bb * C_OUT + co) << 16) + ((size_t)p << 8) + col0 + t] = acc[ml][nt][reg];
      }
    }
  }
}

extern "C" void kernel_launch(void* const* d_in, const int* in_sizes, int n_in,
                              void* d_out, int out_size, void* d_ws, size_t ws_size,
                              hipStream_t stream) {
  const float* x   = (const float*)d_in[0];   // [2,64,256,256]
  const float* s   = (const float*)d_in[1];   // [2,128,16,16]
  const float* s2w = (const float*)d_in[2];   // [36864,128]
  float* out = (float*)d_out;

  char* ws = (char*)d_ws;
  unsigned short* wbuf = (unsigned short*)(ws);              // 37,748,736 B
  unsigned short* sT   = (unsigned short*)(ws + 37748736);   //    131,072 B
  unsigned short* xT   = (unsigned short*)(ws + 37879808);   // 16,777,216 B (total 54.7 MB)

  prep_xs<<<512, 256, 0, stream>>>(x, s, xT, sT);
  wgen_kernel<<<288, 256, 0, stream>>>(s2w, sT, wbuf);
  conv_kernel<<<N_PATCH, 512, 0, stream>>>(xT, wbuf, out);
}

// Round 6
// 135.710 us; speedup vs baseline: 1.0660x; 1.0660x over previous
//
#include <hip/hip_runtime.h>
#include <hip/hip_bf16.h>

// HyperPatchConv2d: B=2, CIN=COUT=64, H=W=256, FH=FW=16 (16x16 patches), SC=128, K=3, reflect pad.
// Pipeline (3 kernels):
//   prep_xs: x fp32 -> xT bf16 channel-last [b][h][w][64ci]; blocks 0-1 also build
//            sT bf16 [512 patch][128 k] from s.
//   wgen:    MFMA GEMM, 128m x 64n tiles, grid (288, 8). s2w is L3-resident (18.9 MB), so
//            n-parallel re-reads are L3 hits, NOT HBM over-fetch (learned R5: n-loop inside
//            block starved occupancy for a phantom BW win). M-index == conv frag offset o:
//              o = fragidx*512 + lane*8 + j, fragidx=(tap*2+ks)*4+mt, lane=(co&15)+16*quad,
//              ci = ks*32+quad*8+j, co = mt*16+(lane&15), p(s2w row) = co*576+ci*9+tap.
//            Epilogue transposes C through LDS (reusing As) -> contiguous 256B store/patch.
//   conv:    per-patch 9-tap MFMA GEMM; 8 waves, wave owns mt-pair (w&1) x row-quarter (w>>1).

#define C_OUT 64
#define C_IN  64
#define P_TOTAL 36864
#define N_PATCH 512
#define WSTR 72          // shorts per (r,c) cell in conv window LDS (144B)
#define GPLANE 1032      // shorts per k8-plane, A (128 rows x 8 + 8 pad; 516 dw = 4 mod 32)
#define BPLANE 520       // shorts per k8-plane, B (64 rows x 8 + 8 pad; 260 dw = 4 mod 32)
#define CSTR 136         // shorts per patch-row in epilogue LDS (272B, 16B-aligned)

typedef __bf16 bf16x8 __attribute__((ext_vector_type(8)));
typedef float  f32x4  __attribute__((ext_vector_type(4)));

__device__ __forceinline__ unsigned short f2bf(float f) {
  unsigned int u = __float_as_uint(f);
  u += 0x7fffu + ((u >> 16) & 1u);   // RTNE on bf16 boundary
  return (unsigned short)(u >> 16);
}

// ---------- prep: x -> xT (all blocks); s -> sT (blocks 0-1) ----------
__global__ __launch_bounds__(256) void prep_xs(
    const float* __restrict__ x, const float* __restrict__ s,
    unsigned short* __restrict__ xT, unsigned short* __restrict__ sT) {
  __shared__ unsigned short lds[256 * 68];
  const int bb = blockIdx.x >> 8;
  const int row = blockIdx.x & 255;
  const int t = threadIdx.x;
  const float* src = x + ((size_t)bb * 64) * 65536 + row * 256 + t;
  #pragma unroll 8
  for (int ci = 0; ci < 64; ++ci)
    lds[t * 68 + ci] = f2bf(src[(size_t)ci * 65536]);
  __syncthreads();
  unsigned short* dst = xT + ((size_t)(bb * 65536 + row * 256 + t)) * 64;
  #pragma unroll
  for (int k8 = 0; k8 < 8; ++k8) {
    const uint2 u0 = *(const uint2*)&lds[t * 68 + k8 * 8];
    const uint2 u1 = *(const uint2*)&lds[t * 68 + k8 * 8 + 4];
    *(uint4*)(dst + k8 * 8) = make_uint4(u0.x, u0.y, u1.x, u1.y);
  }
  if (blockIdx.x < 2) {   // fold in prep_s: one block per batch
    const int sb = blockIdx.x;
    unsigned short* sd = sT + ((size_t)sb * 256 + t) * 128;
    for (int k = 0; k < 128; k += 2) {
      const float a = s[(size_t)(sb * 128 + k) * 256 + t];
      const float b = s[(size_t)(sb * 128 + k + 1) * 256 + t];
      *(unsigned int*)(sd + k) = (unsigned int)f2bf(a) | ((unsigned int)f2bf(b) << 16);
    }
  }
}

// ---------- wgen: MFMA GEMM, 128m x 64n tile, grid (288, 8) ----------
__global__ __launch_bounds__(256) void wgen_kernel(
    const float* __restrict__ s2w,          // fp32 [36864][128]
    const unsigned short* __restrict__ sT,  // bf16 [512][128]
    unsigned short* __restrict__ wout)      // bf16 frags [512][36864], offset o == m
{
  __shared__ unsigned short As[16 * GPLANE];   // 33.0 KB; reused as Ct in epilogue
  __shared__ unsigned short Bs[16 * BPLANE];   // 16.6 KB
  const int tid = threadIdx.x;
  const int m0 = blockIdx.x * 128;   // 288 m-tiles
  const int n0 = blockIdx.y * 64;    // 8 n-tiles

  const int fragidx = m0 >> 9;       // 128-m tile stays inside one 512-m fragidx group
  const int tap = fragidx >> 3;
  const int ksH = (fragidx >> 2) & 1;
  const int mtH = fragidx & 3;

  // A staging: permute + f2bf from fp32 s2w (L3-resident after first n-pass)
  #pragma unroll
  for (int i = 0; i < 8; ++i) {
    const int chunk = i * 256 + tid;        // 2048 chunks: 128 rows x 16 planes
    const int row = chunk >> 4;
    const int g = chunk & 15;
    const int m = m0 + row;
    const int j = m & 7;
    const int lane6 = (m >> 3) & 63;
    const int co = mtH * 16 + (lane6 & 15);
    const int ci = ksH * 32 + (lane6 >> 4) * 8 + j;
    const int p = co * 576 + ci * 9 + tap;
    const float* srcp = s2w + (size_t)p * 128 + g * 8;
    const float4 v0 = *(const float4*)srcp;
    const float4 v1 = *(const float4*)(srcp + 4);
    uint4 o;
    o.x = (unsigned int)f2bf(v0.x) | ((unsigned int)f2bf(v0.y) << 16);
    o.y = (unsigned int)f2bf(v0.z) | ((unsigned int)f2bf(v0.w) << 16);
    o.z = (unsigned int)f2bf(v1.x) | ((unsigned int)f2bf(v1.y) << 16);
    o.w = (unsigned int)f2bf(v1.z) | ((unsigned int)f2bf(v1.w) << 16);
    *(uint4*)&As[g * GPLANE + row * 8] = o;
  }
  // B staging: 64 rows x 16 planes = 1024 chunks
  #pragma unroll
  for (int i = 0; i < 4; ++i) {
    const int chunk = i * 256 + tid;
    const int row = chunk >> 4;
    const int g = chunk & 15;
    *(uint4*)&Bs[g * BPLANE + row * 8] = *(const uint4*)(sT + ((size_t)(n0 + row)) * 128 + g * 8);
  }
  __syncthreads();

  const int wave = tid >> 6;
  const int lane = tid & 63;
  const int col = lane & 15;
  const int quad = lane >> 4;

  f32x4 acc[2][4] = {};              // [mti][nt]
  #pragma unroll
  for (int ks = 0; ks < 4; ++ks) {
    const int g = ks * 4 + quad;
    bf16x8 afr[2], bfr[4];
    #pragma unroll
    for (int mti = 0; mti < 2; ++mti)
      afr[mti] = *(const bf16x8*)&As[g * GPLANE + ((wave * 2 + mti) * 16 + col) * 8];
    #pragma unroll
    for (int nt = 0; nt < 4; ++nt)
      bfr[nt] = *(const bf16x8*)&Bs[g * BPLANE + (nt * 16 + col) * 8];
    #pragma unroll
    for (int mti = 0; mti < 2; ++mti)
      #pragma unroll
      for (int nt = 0; nt < 4; ++nt)
        acc[mti][nt] = __builtin_amdgcn_mfma_f32_16x16x32_bf16(afr[mti], bfr[nt], acc[mti][nt], 0, 0, 0);
  }
  __syncthreads();                   // all A/B frag reads done; As becomes Ct

  // Epilogue: transpose 128m x 64patch through LDS -> contiguous 256B store per patch
  unsigned short* Ct = As;           // [64 patch][CSTR] = 17.4 KB
  #pragma unroll
  for (int mti = 0; mti < 2; ++mti) {
    const int mloc = (wave * 2 + mti) * 16 + quad * 4;
    #pragma unroll
    for (int nt = 0; nt < 4; ++nt) {
      const int pl = nt * 16 + col;  // 0..63
      ushort4 o;
      o.x = f2bf(acc[mti][nt][0]); o.y = f2bf(acc[mti][nt][1]);
      o.z = f2bf(acc[mti][nt][2]); o.w = f2bf(acc[mti][nt][3]);
      *(ushort4*)&Ct[pl * CSTR + mloc] = o;
    }
  }
  __syncthreads();
  #pragma unroll
  for (int i = 0; i < 4; ++i) {
    const int chunk = i * 256 + tid;      // 1024: 64 patches x 16 chunks of 16B
    const int pl = chunk >> 4;
    const int ii = chunk & 15;
    const uint4 v = *(const uint4*)&Ct[pl * CSTR + ii * 8];
    *(uint4*)(wout + (size_t)(n0 + pl) * P_TOTAL + m0 + ii * 8) = v;
  }
}

// ---------- conv: per-patch MFMA; wave = (mt-pair, row-quarter) ----------
__global__ __launch_bounds__(512) void conv_kernel(
    const unsigned short* __restrict__ xT,     // bf16 [2][256][256][64]
    const unsigned short* __restrict__ wfrag,  // bf16 frags [512][36864]
    float* __restrict__ out)                   // [2][64][256][256]
{
  __shared__ unsigned short win[324 * WSTR];   // 46656 B
  const int tid = threadIdx.x;
  const int patch = blockIdx.x;
  const int bb = patch >> 8;
  const int fg = patch & 255;
  const int f = fg >> 4, g = fg & 15;
  const int row0 = f * 16, col0 = g * 16;

  for (int chunk = tid; chunk < 2592; chunk += 512) {
    const int cell = chunk >> 3;
    const int j = chunk & 7;
    const int r = cell / 18;
    const int c = cell - r * 18;
    int rr = row0 + r - 1; rr = rr < 0 ? -rr : (rr > 255 ? 510 - rr : rr);
    int cc = col0 + c - 1; cc = cc < 0 ? -cc : (cc > 255 ? 510 - cc : cc);
    *(uint4*)&win[cell * WSTR + j * 8] =
        *(const uint4*)(xT + ((size_t)((bb << 16) + (rr << 8) + cc)) * 64 + j * 8);
  }
  __syncthreads();

  const int wave = tid >> 6;
  const int lane = tid & 63;
  const int t = lane & 15;
  const int quad = lane >> 4;
  const int mh = wave & 1;        // mt pair: mh*2 + {0,1}
  const int rq = wave >> 1;       // rows rq*4 + {0..3}

  f32x4 acc[2][4] = {};           // [ml][nt]
  const bf16x8* wb = (const bf16x8*)(wfrag + (size_t)patch * P_TOTAL);

  #pragma unroll
  for (int tap = 0; tap < 9; ++tap) {
    const int ti = tap / 3;
    const int tj = tap - ti * 3;
    bf16x8 afr[2][2];
    #pragma unroll
    for (int ks = 0; ks < 2; ++ks)
      #pragma unroll
      for (int ml = 0; ml < 2; ++ml)
        afr[ks][ml] = wb[((tap * 2 + ks) * 4 + mh * 2 + ml) * 64 + lane];

    #pragma unroll
    for (int nt = 0; nt < 4; ++nt) {
      const int r = rq * 4 + nt + ti;
      const int c = t + tj;
      const int base = (r * 18 + c) * WSTR + quad * 8;
      #pragma unroll
      for (int ks = 0; ks < 2; ++ks) {
        const bf16x8 bfr = *(const bf16x8*)&win[base + ks * 32];
        acc[0][nt] = __builtin_amdgcn_mfma_f32_16x16x32_bf16(afr[ks][0], bfr, acc[0][nt], 0, 0, 0);
        acc[1][nt] = __builtin_amdgcn_mfma_f32_16x16x32_bf16(afr[ks][1], bfr, acc[1][nt], 0, 0, 0);
      }
    }
  }

  #pragma unroll
  for (int ml = 0; ml < 2; ++ml) {
    #pragma unroll
    for (int nt = 0; nt < 4; ++nt) {
      const int p = row0 + rq * 4 + nt;
      #pragma unroll
      for (int reg = 0; reg < 4; ++reg) {
        const int co = (mh * 2 + ml) * 16 + quad * 4 + reg;
        out[(((size_t)bb * C_OUT + co) << 16) + ((size_t)p << 8) + col0 + t] = acc[ml][nt][reg];
      }
    }
  }
}

extern "C" void kernel_launch(void* const* d_in, const int* in_sizes, int n_in,
                              void* d_out, int out_size, void* d_ws, size_t ws_size,
                              hipStream_t stream) {
  const float* x   = (const float*)d_in[0];   // [2,64,256,256]
  const float* s   = (const float*)d_in[1];   // [2,128,16,16]
  const float* s2w = (const float*)d_in[2];   // [36864,128]
  float* out = (float*)d_out;

  char* ws = (char*)d_ws;
  unsigned short* wbuf = (unsigned short*)(ws);              // 37,748,736 B
  unsigned short* sT   = (unsigned short*)(ws + 37748736);   //    131,072 B
  unsigned short* xT   = (unsigned short*)(ws + 37879808);   // 16,777,216 B (total 54.7 MB)

  prep_xs<<<512, 256, 0, stream>>>(x, s, xT, sT);
  wgen_kernel<<<dim3(288, 8), 256, 0, stream>>>(s2w, sT, wbuf);
  conv_kernel<<<N_PATCH, 512, 0, stream>>>(xT, wbuf, out);
}